// Round 2
// baseline (361.126 us; speedup 1.0000x reference)
//
#include <hip/hip_runtime.h>
#include <hip/hip_bf16.h>
#include <stdint.h>

// LatticeMultiHeadAttention on MI355X (gfx950). Harness dtype = float32 in/out
// (round-1 NaN proved d_out is read as f32). Internally bf16 MFMA, f32 accum;
// tolerance is absmax_ref/50 = 6.05e-3 absolute -> bf16 pipeline is safe.
//
// Softmax-shift-invariance: per-head phase bias is constant along the softmax
// axis -> Kuramoto inputs (d_in[8..11]) provably don't affect the output.
//
// Pipeline:
//   pack_w : f32 Wq/Wk/Wv (head-blocked) and Wo -> bf16 WT[n][k] in ws
//   cvt_x  : f32 query/key_/value -> bf16 copies in ws
//   gemm_k : D[m=feat][n=row] = WT * X^T (both operands k-contig, global_load_lds)
//            type0 -> Q/K as [b,h,l,dk]; type1 -> V^T [b,h,dk,l]; type2 -> f32 out+bias
//   attn_k : per (b,h) 64 q-rows/block; S^T = K Q^T; no-max softmax (|logit|<=~7);
//            O^T = V^T P^T via per-wave LDS P tile.

typedef unsigned short u16;
typedef __bf16 bf16_t;
typedef bf16_t bf16x8 __attribute__((ext_vector_type(8)));
typedef float f32x4 __attribute__((ext_vector_type(4)));

#define DEVI static __device__ __forceinline__
#define MFMA16(a, b, c) __builtin_amdgcn_mfma_f32_16x16x32_bf16((a), (b), (c), 0, 0, 0)

DEVI void gload_lds16(const void* g, void* l) {
  __builtin_amdgcn_global_load_lds((__attribute__((address_space(1))) void*)g,
                                   (__attribute__((address_space(3))) void*)l, 16, 0, 0);
}

DEVI u16 f2bf(float x) {
  bf16_t b = (bf16_t)x;
  u16 u;
  __builtin_memcpy(&u, &b, 2);
  return u;
}

// ---------------------------------------------------------------------------
// Weight pack (f32 -> bf16): WTq/WTk/WTv[n=h*64+j][k]=W[h][k][j]; WoT[c][d]=Wo[d][c]
__global__ __launch_bounds__(256) void pack_w(const float* __restrict__ Wq,
                                              const float* __restrict__ Wk,
                                              const float* __restrict__ Wv,
                                              const float* __restrict__ Wo,
                                              u16* __restrict__ ws) {
  int id = blockIdx.x * 256 + threadIdx.x;  // 0..524287, 8 elems each
  int mat = id >> 17;
  int rem = id & 131071;
  const float* src = (mat == 0) ? Wq : (mat == 1) ? Wk : (mat == 2) ? Wv : Wo;
  u16* dst = ws + (size_t)mat * 1048576;
  if (mat < 3) {
    int jb = rem & 7;
    int k = (rem >> 3) & 1023;
    int h = rem >> 13;
    const float* s = src + h * 65536 + k * 64 + jb * 8;
    float4 a = *(const float4*)s;
    float4 b = *(const float4*)(s + 4);
    float v[8] = {a.x, a.y, a.z, a.w, b.x, b.y, b.z, b.w};
#pragma unroll
    for (int jj = 0; jj < 8; jj++)
      dst[(size_t)(h * 64 + jb * 8 + jj) * 1024 + k] = f2bf(v[jj]);
  } else {
    int cb = rem & 127;
    int d = rem >> 7;
    const float* s = src + d * 1024 + cb * 8;
    float4 a = *(const float4*)s;
    float4 b = *(const float4*)(s + 4);
    float v[8] = {a.x, a.y, a.z, a.w, b.x, b.y, b.z, b.w};
#pragma unroll
    for (int jj = 0; jj < 8; jj++)
      dst[(size_t)(cb * 8 + jj) * 1024 + d] = f2bf(v[jj]);
  }
}

// ---------------------------------------------------------------------------
// Activations f32 -> bf16 (query, key_, value -> Xq, Xk, Xv; contiguous in ws)
__global__ __launch_bounds__(256) void cvt_x(const float* __restrict__ q,
                                             const float* __restrict__ k,
                                             const float* __restrict__ v,
                                             u16* __restrict__ dst) {
  int id = blockIdx.x * 256 + threadIdx.x;  // 0..6291455, 4 elems each
  int t = id >> 21;
  size_t rem = (size_t)(id & 2097151) * 4;
  const float* src = (t == 0) ? q : (t == 1) ? k : v;
  float4 a = *(const float4*)(src + rem);
  ushort4 st;
  st.x = f2bf(a.x); st.y = f2bf(a.y); st.z = f2bf(a.z); st.w = f2bf(a.w);
  *(ushort4*)(dst + (size_t)t * 8388608 + rem) = st;
}

// ---------------------------------------------------------------------------
// GEMM: D[m][n] = sum_k A[m][k]*B[n][k]; M=1024, N=8192, K=1024 (m97 structure)
__global__ __launch_bounds__(256) void gemm_k(const u16* __restrict__ A,
                                              const u16* __restrict__ Bx,
                                              u16* __restrict__ outb,
                                              float* __restrict__ outf,
                                              const float* __restrict__ bias,
                                              int type) {
  __shared__ __align__(16) u16 sA[128 * 32];
  __shared__ __align__(16) u16 sB[128 * 32];
  int tid = threadIdx.x;
  int wid = tid >> 6, lane = tid & 63, quad = lane >> 4, l16 = lane & 15;
  int wm = wid >> 1, wn = wid & 1;
  int m0 = blockIdx.x * 128, n0 = blockIdx.y * 128;

  f32x4 acc[4][4];
#pragma unroll
  for (int i = 0; i < 4; i++)
#pragma unroll
    for (int j = 0; j < 4; j++) acc[i][j] = {0.f, 0.f, 0.f, 0.f};

  for (int k0 = 0; k0 < 1024; k0 += 32) {
#pragma unroll
    for (int p = 0; p < 2; p++) {
      int cl = p * 256 + tid;
      int r = cl >> 2, kc = cl & 3;
      char* la = (char*)sA + (p * 256 + wid * 64) * 16;
      char* lb = (char*)sB + (p * 256 + wid * 64) * 16;
      gload_lds16(A + (size_t)(m0 + r) * 1024 + k0 + kc * 8, la);
      gload_lds16(Bx + (size_t)(n0 + r) * 1024 + k0 + kc * 8, lb);
    }
    __syncthreads();
    bf16x8 af[4], bfr[4];
#pragma unroll
    for (int mt = 0; mt < 4; mt++)
      af[mt] = *(const bf16x8*)((const char*)sA + ((wm * 64 + mt * 16 + l16) * 64 + quad * 16));
#pragma unroll
    for (int nt = 0; nt < 4; nt++)
      bfr[nt] = *(const bf16x8*)((const char*)sB + ((wn * 64 + nt * 16 + l16) * 64 + quad * 16));
#pragma unroll
    for (int mt = 0; mt < 4; mt++)
#pragma unroll
      for (int nt = 0; nt < 4; nt++) acc[mt][nt] = MFMA16(af[mt], bfr[nt], acc[mt][nt]);
    __syncthreads();
  }

  // C layout: col(n)=l16, row(m)=quad*4+reg
#pragma unroll
  for (int mt = 0; mt < 4; mt++) {
    int m = m0 + wm * 64 + mt * 16 + quad * 4;
#pragma unroll
    for (int nt = 0; nt < 4; nt++) {
      int n = n0 + wn * 64 + nt * 16 + l16;
      f32x4 v = acc[mt][nt];
      if (type == 0) {  // Q/K: [b,h,l,dk] bf16
        int b = n >> 10, l = n & 1023, h = m >> 6, dk = m & 63;
        ushort4 st;
        st.x = f2bf(v[0]); st.y = f2bf(v[1]); st.z = f2bf(v[2]); st.w = f2bf(v[3]);
        *(ushort4*)(outb + ((size_t)((b * 16 + h) * 1024 + l) * 64 + dk)) = st;
      } else if (type == 1) {  // V^T: [b,h,dk,l] bf16
        int b = n >> 10, l = n & 1023, h = m >> 6, dk = m & 63;
        size_t base = ((size_t)((b * 16 + h) * 64 + dk)) * 1024 + l;
        outb[base] = f2bf(v[0]);
        outb[base + 1024] = f2bf(v[1]);
        outb[base + 2048] = f2bf(v[2]);
        outb[base + 3072] = f2bf(v[3]);
      } else {  // out-proj: f32 out[row][d] + bias[d]
        float4 st;
        st.x = v[0] + bias[m];
        st.y = v[1] + bias[m + 1];
        st.z = v[2] + bias[m + 2];
        st.w = v[3] + bias[m + 3];
        *(float4*)(outf + ((size_t)n * 1024 + m)) = st;
      }
    }
  }
}

// ---------------------------------------------------------------------------
// Attention: block = 4 waves, 64 q-rows of one (b,h). Wave w owns q=w*16+l16.
// S^T = K Q^T; exp without max-sub; P -> per-wave LDS [q][lk] (stride 72 u16);
// O^T = V^T P^T. 128B-row LDS tiles use 16B-chunk XOR swizzle (chunk^(row&7)).
__global__ __launch_bounds__(256) void attn_k(const u16* __restrict__ Q,
                                              const u16* __restrict__ K,
                                              const u16* __restrict__ VT,
                                              u16* __restrict__ CTX) {
  __shared__ __align__(16) u16 sQ[64 * 64];
  __shared__ __align__(16) u16 sK[64 * 64];
  __shared__ __align__(16) u16 sV[64 * 64];
  __shared__ __align__(16) u16 sP[4][16 * 72];
  int tid = threadIdx.x;
  int wid = tid >> 6, lane = tid & 63, quad = lane >> 4, l16 = lane & 15;
  int qt = blockIdx.x, bh = blockIdx.y;
  const u16* Qb = Q + (size_t)bh * 65536;
  const u16* Kb = K + (size_t)bh * 65536;
  const u16* Vb = VT + (size_t)bh * 65536;
  int q0 = qt * 64;

#pragma unroll
  for (int p = 0; p < 2; p++) {
    int cl = p * 256 + tid;
    int r = cl >> 3, c = cl & 7, g = c ^ (r & 7);
    gload_lds16(Qb + (size_t)(q0 + r) * 64 + g * 8, (char*)sQ + (p * 256 + wid * 64) * 16);
  }
  __syncthreads();

  bf16x8 bq[2];
  {
    int row = wid * 16 + l16;
#pragma unroll
    for (int ks = 0; ks < 2; ks++) {
      int ch = (ks * 4 + quad) ^ (row & 7);
      bq[ks] = *(const bf16x8*)((const char*)sQ + row * 128 + ch * 16);
    }
  }

  f32x4 oacc[4];
#pragma unroll
  for (int i = 0; i < 4; i++) oacc[i] = {0.f, 0.f, 0.f, 0.f};
  float lsum = 0.f;
  u16* sPw = sP[wid];

  for (int lk0 = 0; lk0 < 1024; lk0 += 64) {
#pragma unroll
    for (int p = 0; p < 2; p++) {
      int cl = p * 256 + tid;
      int r = cl >> 3, c = cl & 7, g = c ^ (r & 7);
      gload_lds16(Kb + (size_t)(lk0 + r) * 64 + g * 8, (char*)sK + (p * 256 + wid * 64) * 16);
      gload_lds16(Vb + (size_t)r * 1024 + lk0 + g * 8, (char*)sV + (p * 256 + wid * 64) * 16);
    }
    __syncthreads();

    f32x4 s[4];
#pragma unroll
    for (int mt = 0; mt < 4; mt++) s[mt] = {0.f, 0.f, 0.f, 0.f};
#pragma unroll
    for (int ks = 0; ks < 2; ks++) {
#pragma unroll
      for (int mt = 0; mt < 4; mt++) {
        int row = mt * 16 + l16;
        int ch = (ks * 4 + quad) ^ (row & 7);
        bf16x8 a = *(const bf16x8*)((const char*)sK + row * 128 + ch * 16);
        s[mt] = MFMA16(a, bq[ks], s[mt]);
      }
    }

#pragma unroll
    for (int mt = 0; mt < 4; mt++) {
      float p0 = __expf(s[mt][0] * 0.125f);
      float p1 = __expf(s[mt][1] * 0.125f);
      float p2 = __expf(s[mt][2] * 0.125f);
      float p3 = __expf(s[mt][3] * 0.125f);
      lsum += (p0 + p1) + (p2 + p3);
      ushort4 st;
      st.x = f2bf(p0); st.y = f2bf(p1); st.z = f2bf(p2); st.w = f2bf(p3);
      *(ushort4*)((char*)sPw + l16 * 144 + mt * 32 + quad * 8) = st;
    }
    asm volatile("s_waitcnt lgkmcnt(0)" ::: "memory");  // same-wave P write->read

    bf16x8 bp[2];
#pragma unroll
    for (int ks = 0; ks < 2; ks++)
      bp[ks] = *(const bf16x8*)((const char*)sPw + l16 * 144 + ks * 64 + quad * 16);
#pragma unroll
    for (int ks = 0; ks < 2; ks++) {
#pragma unroll
      for (int mt = 0; mt < 4; mt++) {
        int row = mt * 16 + l16;
        int ch = (ks * 4 + quad) ^ (row & 7);
        bf16x8 a = *(const bf16x8*)((const char*)sV + row * 128 + ch * 16);
        oacc[mt] = MFMA16(a, bp[ks], oacc[mt]);
      }
    }
    __syncthreads();
  }

  lsum += __shfl_xor(lsum, 16, 64);
  lsum += __shfl_xor(lsum, 32, 64);
  float inv = 1.f / lsum;

  int b = bh >> 4, h = bh & 15;
  int qg = q0 + wid * 16 + l16;
#pragma unroll
  for (int mt = 0; mt < 4; mt++) {
    int dk = mt * 16 + quad * 4;
    ushort4 st;
    st.x = f2bf(oacc[mt][0] * inv);
    st.y = f2bf(oacc[mt][1] * inv);
    st.z = f2bf(oacc[mt][2] * inv);
    st.w = f2bf(oacc[mt][3] * inv);
    *(ushort4*)(CTX + (((size_t)(b * 1024 + qg) * 16 + h) * 64 + dk)) = st;
  }
}

// ---------------------------------------------------------------------------
extern "C" void kernel_launch(void* const* d_in, const int* in_sizes, int n_in,
                              void* d_out, int out_size, void* d_ws, size_t ws_size,
                              hipStream_t stream) {
  (void)in_sizes; (void)n_in; (void)out_size; (void)ws_size;
  const float* query = (const float*)d_in[0];
  const float* key_ = (const float*)d_in[1];
  const float* value = (const float*)d_in[2];
  const float* Wq = (const float*)d_in[3];
  const float* Wk = (const float*)d_in[4];
  const float* Wv = (const float*)d_in[5];
  const float* Wo = (const float*)d_in[6];
  const float* bo = (const float*)d_in[7];
  // d_in[8..11] (phases/freqs/lattice) are softmax-shift-invariant: unused.

  u16* ws = (u16*)d_ws;
  u16* WTq = ws;                  // [1024][1024] bf16
  u16* WTk = ws + 1048576;
  u16* WTv = ws + 2097152;
  u16* WoT = ws + 3145728;
  u16* Xq = ws + 4194304;         // bf16 activations [8192][1024]
  u16* Xk = ws + 12582912;
  u16* Xv = ws + 20971520;
  u16* Qw = ws + 29360128;        // [B,H,L,DK]
  u16* Kw = ws + 37748736;        // [B,H,L,DK]
  u16* Vw = Xk;                   // alias: Xk consumed before V-gemm writes
  u16* Cw = Xq;                   // alias: Xq consumed before attn writes
  float* outp = (float*)d_out;

  pack_w<<<2048, 256, 0, stream>>>(Wq, Wk, Wv, Wo, ws);
  cvt_x<<<24576, 256, 0, stream>>>(query, key_, value, Xq);
  gemm_k<<<dim3(8, 64), 256, 0, stream>>>(WTq, Xq, Qw, nullptr, nullptr, 0);
  gemm_k<<<dim3(8, 64), 256, 0, stream>>>(WTk, Xk, Kw, nullptr, nullptr, 0);
  gemm_k<<<dim3(8, 64), 256, 0, stream>>>(WTv, Xv, Vw, nullptr, nullptr, 1);
  attn_k<<<dim3(16, 128), 256, 0, stream>>>(Qw, Kw, Vw, Cw);
  gemm_k<<<dim3(8, 64), 256, 0, stream>>>(WoT, Cw, nullptr, outp, bo, 2);
}

// Round 3
// 328.066 us; speedup vs baseline: 1.1008x; 1.1008x over previous
//
#include <hip/hip_runtime.h>
#include <hip/hip_bf16.h>
#include <stdint.h>

// LatticeMultiHeadAttention on MI355X (gfx950). f32 in/out, bf16 MFMA inside.
// Kuramoto phase inputs are softmax-shift-invariant -> unused.
//
// R3: attn restructured for LDS-BW (32 q/wave => A-frag reuse x2, sP aliased
// into dead sQ, 4 blocks/CU); QKV projections merged into one dispatch
// (ws-guarded); 1/sqrt(dk) folded into Q projection; pack+cvt merged.

typedef unsigned short u16;
typedef __bf16 bf16_t;
typedef bf16_t bf16x8 __attribute__((ext_vector_type(8)));
typedef float f32x4 __attribute__((ext_vector_type(4)));

#define DEVI static __device__ __forceinline__
#define MFMA16(a, b, c) __builtin_amdgcn_mfma_f32_16x16x32_bf16((a), (b), (c), 0, 0, 0)

DEVI void gload_lds16(const void* g, void* l) {
  __builtin_amdgcn_global_load_lds((__attribute__((address_space(1))) void*)g,
                                   (__attribute__((address_space(3))) void*)l, 16, 0, 0);
}

DEVI u16 f2bf(float x) {
  bf16_t b = (bf16_t)x;
  u16 u;
  __builtin_memcpy(&u, &b, 2);
  return u;
}

// ---------------------------------------------------------------------------
// prep: [blocks 0..2047]  f32 W -> bf16 WT[n][k] (Wq/Wk/Wv head-deblocked, Wo^T)
//       [blocks 2048..26623] f32 activations -> bf16 X copies
__global__ __launch_bounds__(256) void prep(const float* __restrict__ Wq,
                                            const float* __restrict__ Wk,
                                            const float* __restrict__ Wv,
                                            const float* __restrict__ Wo,
                                            const float* __restrict__ q,
                                            const float* __restrict__ k,
                                            const float* __restrict__ v,
                                            u16* __restrict__ ws) {
  int bx = blockIdx.x;
  if (bx < 2048) {
    int id = bx * 256 + threadIdx.x;  // 0..524287, 8 elems each
    int mat = id >> 17;
    int rem = id & 131071;
    const float* src = (mat == 0) ? Wq : (mat == 1) ? Wk : (mat == 2) ? Wv : Wo;
    u16* dst = ws + (size_t)mat * 1048576;
    if (mat < 3) {
      int jb = rem & 7;
      int kk = (rem >> 3) & 1023;
      int h = rem >> 13;
      const float* s = src + h * 65536 + kk * 64 + jb * 8;
      float4 a = *(const float4*)s;
      float4 b = *(const float4*)(s + 4);
      float vv[8] = {a.x, a.y, a.z, a.w, b.x, b.y, b.z, b.w};
#pragma unroll
      for (int jj = 0; jj < 8; jj++)
        dst[(size_t)(h * 64 + jb * 8 + jj) * 1024 + kk] = f2bf(vv[jj]);
    } else {
      int cb = rem & 127;
      int d = rem >> 7;
      const float* s = src + d * 1024 + cb * 8;
      float4 a = *(const float4*)s;
      float4 b = *(const float4*)(s + 4);
      float vv[8] = {a.x, a.y, a.z, a.w, b.x, b.y, b.z, b.w};
#pragma unroll
      for (int jj = 0; jj < 8; jj++)
        dst[(size_t)(cb * 8 + jj) * 1024 + d] = f2bf(vv[jj]);
    }
  } else {
    int id = (bx - 2048) * 256 + threadIdx.x;  // 0..6291455, 4 elems each
    int t = id >> 21;
    size_t rem = (size_t)(id & 2097151) * 4;
    const float* src = (t == 0) ? q : (t == 1) ? k : v;
    float4 a = *(const float4*)(src + rem);
    ushort4 st;
    st.x = f2bf(a.x); st.y = f2bf(a.y); st.z = f2bf(a.z); st.w = f2bf(a.w);
    *(ushort4*)(ws + 4194304 + (size_t)t * 8388608 + rem) = st;
  }
}

// ---------------------------------------------------------------------------
// QKV projections, one dispatch (z = 0:Q, 1:K, 2:V). D[m][n]=sum_k A[m][k]B[n][k].
// Q gets 0.125 scale folded in. z<2 -> [b,h,l,dk]; z=2 -> V^T [b,h,dk,l].
__global__ __launch_bounds__(256) void gemm_qkv(const u16* __restrict__ WT,
                                                const u16* __restrict__ X,
                                                u16* __restrict__ Qw,
                                                u16* __restrict__ Kw,
                                                u16* __restrict__ Vw,
                                                int zoff) {
  __shared__ __align__(16) u16 sA[128 * 32];
  __shared__ __align__(16) u16 sB[128 * 32];
  int z = blockIdx.z + zoff;
  const u16* A = WT + (size_t)z * 1048576;
  const u16* Bx = X + (size_t)z * 8388608;
  u16* out = (z == 0) ? Qw : (z == 1) ? Kw : Vw;
  float oscale = (z == 0) ? 0.125f : 1.0f;

  int tid = threadIdx.x;
  int wid = tid >> 6, lane = tid & 63, quad = lane >> 4, l16 = lane & 15;
  int wm = wid >> 1, wn = wid & 1;
  int m0 = blockIdx.x * 128, n0 = blockIdx.y * 128;

  f32x4 acc[4][4];
#pragma unroll
  for (int i = 0; i < 4; i++)
#pragma unroll
    for (int j = 0; j < 4; j++) acc[i][j] = {0.f, 0.f, 0.f, 0.f};

  for (int k0 = 0; k0 < 1024; k0 += 32) {
#pragma unroll
    for (int p = 0; p < 2; p++) {
      int cl = p * 256 + tid;
      int r = cl >> 2, kc = cl & 3;
      gload_lds16(A + (size_t)(m0 + r) * 1024 + k0 + kc * 8,
                  (char*)sA + (p * 256 + wid * 64) * 16);
      gload_lds16(Bx + (size_t)(n0 + r) * 1024 + k0 + kc * 8,
                  (char*)sB + (p * 256 + wid * 64) * 16);
    }
    __syncthreads();
    bf16x8 af[4], bfr[4];
#pragma unroll
    for (int mt = 0; mt < 4; mt++)
      af[mt] = *(const bf16x8*)((const char*)sA + ((wm * 64 + mt * 16 + l16) * 64 + quad * 16));
#pragma unroll
    for (int nt = 0; nt < 4; nt++)
      bfr[nt] = *(const bf16x8*)((const char*)sB + ((wn * 64 + nt * 16 + l16) * 64 + quad * 16));
#pragma unroll
    for (int mt = 0; mt < 4; mt++)
#pragma unroll
      for (int nt = 0; nt < 4; nt++) acc[mt][nt] = MFMA16(af[mt], bfr[nt], acc[mt][nt]);
    __syncthreads();
  }

#pragma unroll
  for (int mt = 0; mt < 4; mt++) {
    int m = m0 + wm * 64 + mt * 16 + quad * 4;
#pragma unroll
    for (int nt = 0; nt < 4; nt++) {
      int n = n0 + wn * 64 + nt * 16 + l16;
      f32x4 v = acc[mt][nt];
      int b = n >> 10, l = n & 1023, h = m >> 6, dk = m & 63;
      if (z < 2) {
        ushort4 st;
        st.x = f2bf(v[0] * oscale); st.y = f2bf(v[1] * oscale);
        st.z = f2bf(v[2] * oscale); st.w = f2bf(v[3] * oscale);
        *(ushort4*)(out + ((size_t)((b * 16 + h) * 1024 + l) * 64 + dk)) = st;
      } else {
        size_t base = ((size_t)((b * 16 + h) * 64 + dk)) * 1024 + l;
        out[base] = f2bf(v[0]);
        out[base + 1024] = f2bf(v[1]);
        out[base + 2048] = f2bf(v[2]);
        out[base + 3072] = f2bf(v[3]);
      }
    }
  }
}

// ---------------------------------------------------------------------------
// Out-projection: f32 out[row][d] = sum_k WoT[d][k]*Cw[row][k] + bias[d]
__global__ __launch_bounds__(256) void gemm_out(const u16* __restrict__ A,
                                                const u16* __restrict__ Bx,
                                                float* __restrict__ outf,
                                                const float* __restrict__ bias) {
  __shared__ __align__(16) u16 sA[128 * 32];
  __shared__ __align__(16) u16 sB[128 * 32];
  int tid = threadIdx.x;
  int wid = tid >> 6, lane = tid & 63, quad = lane >> 4, l16 = lane & 15;
  int wm = wid >> 1, wn = wid & 1;
  int m0 = blockIdx.x * 128, n0 = blockIdx.y * 128;

  f32x4 acc[4][4];
#pragma unroll
  for (int i = 0; i < 4; i++)
#pragma unroll
    for (int j = 0; j < 4; j++) acc[i][j] = {0.f, 0.f, 0.f, 0.f};

  for (int k0 = 0; k0 < 1024; k0 += 32) {
#pragma unroll
    for (int p = 0; p < 2; p++) {
      int cl = p * 256 + tid;
      int r = cl >> 2, kc = cl & 3;
      gload_lds16(A + (size_t)(m0 + r) * 1024 + k0 + kc * 8,
                  (char*)sA + (p * 256 + wid * 64) * 16);
      gload_lds16(Bx + (size_t)(n0 + r) * 1024 + k0 + kc * 8,
                  (char*)sB + (p * 256 + wid * 64) * 16);
    }
    __syncthreads();
    bf16x8 af[4], bfr[4];
#pragma unroll
    for (int mt = 0; mt < 4; mt++)
      af[mt] = *(const bf16x8*)((const char*)sA + ((wm * 64 + mt * 16 + l16) * 64 + quad * 16));
#pragma unroll
    for (int nt = 0; nt < 4; nt++)
      bfr[nt] = *(const bf16x8*)((const char*)sB + ((wn * 64 + nt * 16 + l16) * 64 + quad * 16));
#pragma unroll
    for (int mt = 0; mt < 4; mt++)
#pragma unroll
      for (int nt = 0; nt < 4; nt++) acc[mt][nt] = MFMA16(af[mt], bfr[nt], acc[mt][nt]);
    __syncthreads();
  }

#pragma unroll
  for (int mt = 0; mt < 4; mt++) {
    int m = m0 + wm * 64 + mt * 16 + quad * 4;
#pragma unroll
    for (int nt = 0; nt < 4; nt++) {
      int n = n0 + wn * 64 + nt * 16 + l16;
      f32x4 v = acc[mt][nt];
      float4 st;
      st.x = v[0] + bias[m];
      st.y = v[1] + bias[m + 1];
      st.z = v[2] + bias[m + 2];
      st.w = v[3] + bias[m + 3];
      *(float4*)(outf + ((size_t)n * 1024 + m)) = st;
    }
  }
}

// ---------------------------------------------------------------------------
// Attention v3: block = 4 waves, 128 q (wave owns 32 q = 2 B-frags).
// S^T = K Q^T (Q pre-scaled); exp (no max-sub, |logit|<=~7); P via per-wave
// region aliased into dead sQ; O^T = V^T P^T. A-frags (K,V) reused across the
// 2 q-frags. All 128B LDS rows use 16B-chunk XOR swizzle (chunk^(row&7)).
__global__ __launch_bounds__(256, 4) void attn_k(const u16* __restrict__ Q,
                                                 const u16* __restrict__ K,
                                                 const u16* __restrict__ VT,
                                                 u16* __restrict__ CTX) {
  __shared__ __align__(16) u16 sQ[128 * 64];  // 16 KB; reused as sP after bq load
  __shared__ __align__(16) u16 sK[64 * 64];   // 8 KB
  __shared__ __align__(16) u16 sV[64 * 64];   // 8 KB
  int tid = threadIdx.x;
  int wid = tid >> 6, lane = tid & 63, quad = lane >> 4, l16 = lane & 15;
  int qt = blockIdx.x, bh = blockIdx.y;
  const u16* Qb = Q + (size_t)bh * 65536;
  const u16* Kb = K + (size_t)bh * 65536;
  const u16* Vb = VT + (size_t)bh * 65536;
  int q0 = qt * 128;

  // stage 128 q rows (16 KB)
#pragma unroll
  for (int p = 0; p < 4; p++) {
    int cl = p * 256 + tid;
    int r = cl >> 3, c = cl & 7, g = c ^ (r & 7);
    gload_lds16(Qb + (size_t)(q0 + r) * 64 + g * 8, (char*)sQ + (p * 256 + wid * 64) * 16);
  }
  __syncthreads();

  // bq[qf][ks]: wave's 32 q rows -> registers (sQ dead afterwards)
  bf16x8 bq[2][2];
#pragma unroll
  for (int qf = 0; qf < 2; qf++) {
    int row = wid * 32 + qf * 16 + l16;
#pragma unroll
    for (int ks = 0; ks < 2; ks++) {
      int ch = (ks * 4 + quad) ^ (row & 7);
      bq[qf][ks] = *(const bf16x8*)((const char*)sQ + row * 128 + ch * 16);
    }
  }
  // no barrier needed: first K-loop __syncthreads (below) drains these reads
  // in-wave before any wave's sP writes (which occur after that barrier).

  u16* sPw = sQ + wid * 2048;  // per-wave 32 rows x 64 lk (4 KB)

  f32x4 oacc[4][2];
#pragma unroll
  for (int i = 0; i < 4; i++) {
    oacc[i][0] = {0.f, 0.f, 0.f, 0.f};
    oacc[i][1] = {0.f, 0.f, 0.f, 0.f};
  }
  float lsum[2] = {0.f, 0.f};

  for (int lk0 = 0; lk0 < 1024; lk0 += 64) {
#pragma unroll
    for (int p = 0; p < 2; p++) {
      int cl = p * 256 + tid;
      int r = cl >> 3, c = cl & 7, g = c ^ (r & 7);
      gload_lds16(Kb + (size_t)(lk0 + r) * 64 + g * 8, (char*)sK + (p * 256 + wid * 64) * 16);
      gload_lds16(Vb + (size_t)r * 1024 + lk0 + g * 8, (char*)sV + (p * 256 + wid * 64) * 16);
    }
    __syncthreads();

    // S^T = K Q^T : 8 A-reads, 16 MFMAs
    f32x4 s[4][2];
#pragma unroll
    for (int mt = 0; mt < 4; mt++) {
      s[mt][0] = {0.f, 0.f, 0.f, 0.f};
      s[mt][1] = {0.f, 0.f, 0.f, 0.f};
    }
#pragma unroll
    for (int ks = 0; ks < 2; ks++) {
#pragma unroll
      for (int mt = 0; mt < 4; mt++) {
        int row = mt * 16 + l16;
        int ch = (ks * 4 + quad) ^ (row & 7);
        bf16x8 a = *(const bf16x8*)((const char*)sK + row * 128 + ch * 16);
        s[mt][0] = MFMA16(a, bq[0][ks], s[mt][0]);
        s[mt][1] = MFMA16(a, bq[1][ks], s[mt][1]);
      }
    }

    // exp + P store (swizzled rows of 128 B)
#pragma unroll
    for (int qf = 0; qf < 2; qf++) {
      int row = qf * 16 + l16;
#pragma unroll
      for (int mt = 0; mt < 4; mt++) {
        float p0 = __expf(s[mt][qf][0]);
        float p1 = __expf(s[mt][qf][1]);
        float p2 = __expf(s[mt][qf][2]);
        float p3 = __expf(s[mt][qf][3]);
        lsum[qf] += (p0 + p1) + (p2 + p3);
        ushort4 st;
        st.x = f2bf(p0); st.y = f2bf(p1); st.z = f2bf(p2); st.w = f2bf(p3);
        int ch = (2 * mt + (quad >> 1)) ^ (row & 7);
        *(ushort4*)((char*)sPw + row * 128 + ch * 16 + (quad & 1) * 8) = st;
      }
    }
    asm volatile("s_waitcnt lgkmcnt(0)" ::: "memory");  // same-wave P write->read

    // O^T += V^T P^T : 8 A-reads, 4 P-reads, 16 MFMAs
    bf16x8 bp[2][2];
#pragma unroll
    for (int qf = 0; qf < 2; qf++) {
      int row = qf * 16 + l16;
#pragma unroll
      for (int c = 0; c < 2; c++) {
        int ch = (c * 4 + quad) ^ (row & 7);
        bp[qf][c] = *(const bf16x8*)((const char*)sPw + row * 128 + ch * 16);
      }
    }
#pragma unroll
    for (int c = 0; c < 2; c++) {
#pragma unroll
      for (int mt = 0; mt < 4; mt++) {
        int row = mt * 16 + l16;
        int ch = (c * 4 + quad) ^ (row & 7);
        bf16x8 a = *(const bf16x8*)((const char*)sV + row * 128 + ch * 16);
        oacc[mt][0] = MFMA16(a, bp[0][c], oacc[mt][0]);
        oacc[mt][1] = MFMA16(a, bp[1][c], oacc[mt][1]);
      }
    }
    __syncthreads();
  }

#pragma unroll
  for (int qf = 0; qf < 2; qf++) {
    lsum[qf] += __shfl_xor(lsum[qf], 16, 64);
    lsum[qf] += __shfl_xor(lsum[qf], 32, 64);
  }
  float inv0 = 1.f / lsum[0], inv1 = 1.f / lsum[1];

  int b = bh >> 4, h = bh & 15;
#pragma unroll
  for (int qf = 0; qf < 2; qf++) {
    int qg = q0 + wid * 32 + qf * 16 + l16;
    float inv = qf ? inv1 : inv0;
#pragma unroll
    for (int mt = 0; mt < 4; mt++) {
      int dk = mt * 16 + quad * 4;
      ushort4 st;
      st.x = f2bf(oacc[mt][qf][0] * inv);
      st.y = f2bf(oacc[mt][qf][1] * inv);
      st.z = f2bf(oacc[mt][qf][2] * inv);
      st.w = f2bf(oacc[mt][qf][3] * inv);
      *(ushort4*)(CTX + (((size_t)(b * 1024 + qg) * 16 + h) * 64 + dk)) = st;
    }
  }
}

// ---------------------------------------------------------------------------
extern "C" void kernel_launch(void* const* d_in, const int* in_sizes, int n_in,
                              void* d_out, int out_size, void* d_ws, size_t ws_size,
                              hipStream_t stream) {
  (void)in_sizes; (void)n_in; (void)out_size;
  const float* query = (const float*)d_in[0];
  const float* key_ = (const float*)d_in[1];
  const float* value = (const float*)d_in[2];
  const float* Wq = (const float*)d_in[3];
  const float* Wk = (const float*)d_in[4];
  const float* Wv = (const float*)d_in[5];
  const float* Wo = (const float*)d_in[6];
  const float* bo = (const float*)d_in[7];

  u16* ws = (u16*)d_ws;
  u16* WT = ws;                   // 4 x [1024][1024] bf16 (WTq,WTk,WTv,WoT)
  u16* X = ws + 4194304;          // 3 x [8192][1024] bf16 (Xq,Xk,Xv)
  u16* Qw = ws + 29360128;        // [B,H,L,DK]
  u16* Kw = ws + 37748736;        // [B,H,L,DK]
  u16* Xk = X + 8388608;
  u16* Cw = X;                    // alias Xq (dead after projections)
  float* outp = (float*)d_out;

  prep<<<26624, 256, 0, stream>>>(Wq, Wk, Wv, Wo, query, key_, value, ws);

  u16* Vw;
  if (ws_size >= 109051905ULL) {
    Vw = ws + 46137344;  // fresh buffer -> merged QKV dispatch is race-free
    gemm_qkv<<<dim3(8, 64, 3), 256, 0, stream>>>(WT, X, Qw, Kw, Vw, 0);
  } else {
    Vw = Xk;  // sequential: V-gemm may overwrite Xk after K-gemm consumed it
    gemm_qkv<<<dim3(8, 64, 1), 256, 0, stream>>>(WT, X, Qw, Kw, Vw, 0);
    gemm_qkv<<<dim3(8, 64, 1), 256, 0, stream>>>(WT, X, Qw, Kw, Vw, 1);
    gemm_qkv<<<dim3(8, 64, 1), 256, 0, stream>>>(WT, X, Qw, Kw, Vw, 2);
  }
  attn_k<<<dim3(8, 128), 256, 0, stream>>>(Qw, Kw, Vw, Cw);
  gemm_out<<<dim3(8, 64), 256, 0, stream>>>(WT + 3145728, Cw, outp, bo);
}

// Round 4
// 308.191 us; speedup vs baseline: 1.1718x; 1.0645x over previous
//
#include <hip/hip_runtime.h>
#include <hip/hip_bf16.h>
#include <stdint.h>

// LatticeMultiHeadAttention on MI355X (gfx950). f32 in/out, bf16 MFMA inside.
// Kuramoto phase inputs are softmax-shift-invariant -> unused.
//
// R4: XCD-aware block swizzle in gemm_qkv / gemm_out / attn_k. Blocks sharing
// an operand tile (X n-tile, K/V of one (b,h), Wo) are remapped to the SAME
// XCD back-to-back so the per-XCD (non-coherent) L2 serves the refetches.
// R3 counters: gemm_qkv FETCH 200 MB vs 54 ideal -> cross-XCD scatter.

typedef unsigned short u16;
typedef __bf16 bf16_t;
typedef bf16_t bf16x8 __attribute__((ext_vector_type(8)));
typedef float f32x4 __attribute__((ext_vector_type(4)));

#define DEVI static __device__ __forceinline__
#define MFMA16(a, b, c) __builtin_amdgcn_mfma_f32_16x16x32_bf16((a), (b), (c), 0, 0, 0)

DEVI void gload_lds16(const void* g, void* l) {
  __builtin_amdgcn_global_load_lds((__attribute__((address_space(1))) void*)g,
                                   (__attribute__((address_space(3))) void*)l, 16, 0, 0);
}

DEVI u16 f2bf(float x) {
  bf16_t b = (bf16_t)x;
  u16 u;
  __builtin_memcpy(&u, &b, 2);
  return u;
}

// ---------------------------------------------------------------------------
// prep: [blocks 0..2047]  f32 W -> bf16 WT[n][k] (Wq/Wk/Wv head-deblocked, Wo^T)
//       [blocks 2048..26623] f32 activations -> bf16 X copies
__global__ __launch_bounds__(256) void prep(const float* __restrict__ Wq,
                                            const float* __restrict__ Wk,
                                            const float* __restrict__ Wv,
                                            const float* __restrict__ Wo,
                                            const float* __restrict__ q,
                                            const float* __restrict__ k,
                                            const float* __restrict__ v,
                                            u16* __restrict__ ws) {
  int bx = blockIdx.x;
  if (bx < 2048) {
    int id = bx * 256 + threadIdx.x;  // 0..524287, 8 elems each
    int mat = id >> 17;
    int rem = id & 131071;
    const float* src = (mat == 0) ? Wq : (mat == 1) ? Wk : (mat == 2) ? Wv : Wo;
    u16* dst = ws + (size_t)mat * 1048576;
    if (mat < 3) {
      int jb = rem & 7;
      int kk = (rem >> 3) & 1023;
      int h = rem >> 13;
      const float* s = src + h * 65536 + kk * 64 + jb * 8;
      float4 a = *(const float4*)s;
      float4 b = *(const float4*)(s + 4);
      float vv[8] = {a.x, a.y, a.z, a.w, b.x, b.y, b.z, b.w};
#pragma unroll
      for (int jj = 0; jj < 8; jj++)
        dst[(size_t)(h * 64 + jb * 8 + jj) * 1024 + kk] = f2bf(vv[jj]);
    } else {
      int cb = rem & 127;
      int d = rem >> 7;
      const float* s = src + d * 1024 + cb * 8;
      float4 a = *(const float4*)s;
      float4 b = *(const float4*)(s + 4);
      float vv[8] = {a.x, a.y, a.z, a.w, b.x, b.y, b.z, b.w};
#pragma unroll
      for (int jj = 0; jj < 8; jj++)
        dst[(size_t)(cb * 8 + jj) * 1024 + d] = f2bf(vv[jj]);
    }
  } else {
    int id = (bx - 2048) * 256 + threadIdx.x;  // 0..6291455, 4 elems each
    int t = id >> 21;
    size_t rem = (size_t)(id & 2097151) * 4;
    const float* src = (t == 0) ? q : (t == 1) ? k : v;
    float4 a = *(const float4*)(src + rem);
    ushort4 st;
    st.x = f2bf(a.x); st.y = f2bf(a.y); st.z = f2bf(a.z); st.w = f2bf(a.w);
    *(ushort4*)(ws + 4194304 + (size_t)t * 8388608 + rem) = st;
  }
}

// ---------------------------------------------------------------------------
// QKV projections, one dispatch. D[m][n]=sum_k A[m][k]B[n][k].
// XCD swizzle: 1536 blocks; xcd=id%8 owns n-groups [xcd*24, xcd*24+24); the 8
// m-tiles of one n-group are consecutive on that XCD (X tile + W stay in L2).
__global__ __launch_bounds__(256) void gemm_qkv(const u16* __restrict__ WT,
                                                const u16* __restrict__ X,
                                                u16* __restrict__ Qw,
                                                u16* __restrict__ Kw,
                                                u16* __restrict__ Vw) {
  __shared__ __align__(16) u16 sA[128 * 32];
  __shared__ __align__(16) u16 sB[128 * 32];
  int id = blockIdx.x + 8 * (blockIdx.y + 64 * blockIdx.z);  // 0..1535
  int xcd = id & 7, j = id >> 3;   // j: 0..191
  int mtile = j & 7;
  int g = xcd * 24 + (j >> 3);     // n-group 0..191 = (z, ntile)
  int z = g >> 6;                  // 0..2
  int nt = g & 63;                 // 0..63
  const u16* A = WT + (size_t)z * 1048576;
  const u16* Bx = X + (size_t)z * 8388608;
  u16* out = (z == 0) ? Qw : (z == 1) ? Kw : Vw;
  float oscale = (z == 0) ? 0.125f : 1.0f;

  int tid = threadIdx.x;
  int wid = tid >> 6, lane = tid & 63, quad = lane >> 4, l16 = lane & 15;
  int wm = wid >> 1, wn = wid & 1;
  int m0 = mtile * 128, n0 = nt * 128;

  f32x4 acc[4][4];
#pragma unroll
  for (int i = 0; i < 4; i++)
#pragma unroll
    for (int jj = 0; jj < 4; jj++) acc[i][jj] = {0.f, 0.f, 0.f, 0.f};

  for (int k0 = 0; k0 < 1024; k0 += 32) {
#pragma unroll
    for (int p = 0; p < 2; p++) {
      int cl = p * 256 + tid;
      int r = cl >> 2, kc = cl & 3;
      gload_lds16(A + (size_t)(m0 + r) * 1024 + k0 + kc * 8,
                  (char*)sA + (p * 256 + wid * 64) * 16);
      gload_lds16(Bx + (size_t)(n0 + r) * 1024 + k0 + kc * 8,
                  (char*)sB + (p * 256 + wid * 64) * 16);
    }
    __syncthreads();
    bf16x8 af[4], bfr[4];
#pragma unroll
    for (int mt = 0; mt < 4; mt++)
      af[mt] = *(const bf16x8*)((const char*)sA + ((wm * 64 + mt * 16 + l16) * 64 + quad * 16));
#pragma unroll
    for (int ntf = 0; ntf < 4; ntf++)
      bfr[ntf] = *(const bf16x8*)((const char*)sB + ((wn * 64 + ntf * 16 + l16) * 64 + quad * 16));
#pragma unroll
    for (int mt = 0; mt < 4; mt++)
#pragma unroll
      for (int ntf = 0; ntf < 4; ntf++) acc[mt][ntf] = MFMA16(af[mt], bfr[ntf], acc[mt][ntf]);
    __syncthreads();
  }

#pragma unroll
  for (int mt = 0; mt < 4; mt++) {
    int m = m0 + wm * 64 + mt * 16 + quad * 4;
#pragma unroll
    for (int ntf = 0; ntf < 4; ntf++) {
      int n = n0 + wn * 64 + ntf * 16 + l16;
      f32x4 v = acc[mt][ntf];
      int b = n >> 10, l = n & 1023, h = m >> 6, dk = m & 63;
      if (z < 2) {
        ushort4 st;
        st.x = f2bf(v[0] * oscale); st.y = f2bf(v[1] * oscale);
        st.z = f2bf(v[2] * oscale); st.w = f2bf(v[3] * oscale);
        *(ushort4*)(out + ((size_t)((b * 16 + h) * 1024 + l) * 64 + dk)) = st;
      } else {
        size_t base = ((size_t)((b * 16 + h) * 64 + dk)) * 1024 + l;
        out[base] = f2bf(v[0]);
        out[base + 1024] = f2bf(v[1]);
        out[base + 2048] = f2bf(v[2]);
        out[base + 3072] = f2bf(v[3]);
      }
    }
  }
}

// ---------------------------------------------------------------------------
// Out-projection: f32 out[row][d] = sum_k WoT[d][k]*Cw[row][k] + bias[d]
// XCD swizzle: 512 blocks; xcd owns n-tiles [xcd*8, xcd*8+8).
__global__ __launch_bounds__(256) void gemm_out(const u16* __restrict__ A,
                                                const u16* __restrict__ Bx,
                                                float* __restrict__ outf,
                                                const float* __restrict__ bias) {
  __shared__ __align__(16) u16 sA[128 * 32];
  __shared__ __align__(16) u16 sB[128 * 32];
  int id = blockIdx.x + 8 * blockIdx.y;  // 0..511
  int xcd = id & 7, j = id >> 3;         // j: 0..63
  int mtile = j & 7;
  int nt = xcd * 8 + (j >> 3);           // 0..63
  int tid = threadIdx.x;
  int wid = tid >> 6, lane = tid & 63, quad = lane >> 4, l16 = lane & 15;
  int wm = wid >> 1, wn = wid & 1;
  int m0 = mtile * 128, n0 = nt * 128;

  f32x4 acc[4][4];
#pragma unroll
  for (int i = 0; i < 4; i++)
#pragma unroll
    for (int jj = 0; jj < 4; jj++) acc[i][jj] = {0.f, 0.f, 0.f, 0.f};

  for (int k0 = 0; k0 < 1024; k0 += 32) {
#pragma unroll
    for (int p = 0; p < 2; p++) {
      int cl = p * 256 + tid;
      int r = cl >> 2, kc = cl & 3;
      gload_lds16(A + (size_t)(m0 + r) * 1024 + k0 + kc * 8,
                  (char*)sA + (p * 256 + wid * 64) * 16);
      gload_lds16(Bx + (size_t)(n0 + r) * 1024 + k0 + kc * 8,
                  (char*)sB + (p * 256 + wid * 64) * 16);
    }
    __syncthreads();
    bf16x8 af[4], bfr[4];
#pragma unroll
    for (int mt = 0; mt < 4; mt++)
      af[mt] = *(const bf16x8*)((const char*)sA + ((wm * 64 + mt * 16 + l16) * 64 + quad * 16));
#pragma unroll
    for (int ntf = 0; ntf < 4; ntf++)
      bfr[ntf] = *(const bf16x8*)((const char*)sB + ((wn * 64 + ntf * 16 + l16) * 64 + quad * 16));
#pragma unroll
    for (int mt = 0; mt < 4; mt++)
#pragma unroll
      for (int ntf = 0; ntf < 4; ntf++) acc[mt][ntf] = MFMA16(af[mt], bfr[ntf], acc[mt][ntf]);
    __syncthreads();
  }

#pragma unroll
  for (int mt = 0; mt < 4; mt++) {
    int m = m0 + wm * 64 + mt * 16 + quad * 4;
#pragma unroll
    for (int ntf = 0; ntf < 4; ntf++) {
      int n = n0 + wn * 64 + ntf * 16 + l16;
      f32x4 v = acc[mt][ntf];
      float4 st;
      st.x = v[0] + bias[m];
      st.y = v[1] + bias[m + 1];
      st.z = v[2] + bias[m + 2];
      st.w = v[3] + bias[m + 3];
      *(float4*)(outf + ((size_t)n * 1024 + m)) = st;
    }
  }
}

// ---------------------------------------------------------------------------
// Attention: block = 4 waves, 128 q (wave owns 32 q = 2 B-frags).
// S^T = K Q^T (Q pre-scaled); exp (no max-sub); P in dead sQ region;
// O^T = V^T P^T. XCD swizzle: the 8 q-blocks of one (b,h) share K/V -> same XCD.
__global__ __launch_bounds__(256, 4) void attn_k(const u16* __restrict__ Q,
                                                 const u16* __restrict__ K,
                                                 const u16* __restrict__ VT,
                                                 u16* __restrict__ CTX) {
  __shared__ __align__(16) u16 sQ[128 * 64];  // 16 KB; reused as sP after bq load
  __shared__ __align__(16) u16 sK[64 * 64];   // 8 KB
  __shared__ __align__(16) u16 sV[64 * 64];   // 8 KB
  int tid = threadIdx.x;
  int wid = tid >> 6, lane = tid & 63, quad = lane >> 4, l16 = lane & 15;
  int id = blockIdx.x + 8 * blockIdx.y;  // 0..1023
  int xcd = id & 7, j = id >> 3;         // j: 0..127
  int qt = j & 7;
  int bh = xcd * 16 + (j >> 3);          // 0..127
  const u16* Qb = Q + (size_t)bh * 65536;
  const u16* Kb = K + (size_t)bh * 65536;
  const u16* Vb = VT + (size_t)bh * 65536;
  int q0 = qt * 128;

#pragma unroll
  for (int p = 0; p < 4; p++) {
    int cl = p * 256 + tid;
    int r = cl >> 3, c = cl & 7, g = c ^ (r & 7);
    gload_lds16(Qb + (size_t)(q0 + r) * 64 + g * 8, (char*)sQ + (p * 256 + wid * 64) * 16);
  }
  __syncthreads();

  bf16x8 bq[2][2];
#pragma unroll
  for (int qf = 0; qf < 2; qf++) {
    int row = wid * 32 + qf * 16 + l16;
#pragma unroll
    for (int ks = 0; ks < 2; ks++) {
      int ch = (ks * 4 + quad) ^ (row & 7);
      bq[qf][ks] = *(const bf16x8*)((const char*)sQ + row * 128 + ch * 16);
    }
  }
  // first K-loop barrier drains these reads before any sP write lands.

  u16* sPw = sQ + wid * 2048;  // per-wave 32 rows x 64 lk (4 KB)

  f32x4 oacc[4][2];
#pragma unroll
  for (int i = 0; i < 4; i++) {
    oacc[i][0] = {0.f, 0.f, 0.f, 0.f};
    oacc[i][1] = {0.f, 0.f, 0.f, 0.f};
  }
  float lsum[2] = {0.f, 0.f};

  for (int lk0 = 0; lk0 < 1024; lk0 += 64) {
#pragma unroll
    for (int p = 0; p < 2; p++) {
      int cl = p * 256 + tid;
      int r = cl >> 3, c = cl & 7, g = c ^ (r & 7);
      gload_lds16(Kb + (size_t)(lk0 + r) * 64 + g * 8, (char*)sK + (p * 256 + wid * 64) * 16);
      gload_lds16(Vb + (size_t)r * 1024 + lk0 + g * 8, (char*)sV + (p * 256 + wid * 64) * 16);
    }
    __syncthreads();

    f32x4 s[4][2];
#pragma unroll
    for (int mt = 0; mt < 4; mt++) {
      s[mt][0] = {0.f, 0.f, 0.f, 0.f};
      s[mt][1] = {0.f, 0.f, 0.f, 0.f};
    }
#pragma unroll
    for (int ks = 0; ks < 2; ks++) {
#pragma unroll
      for (int mt = 0; mt < 4; mt++) {
        int row = mt * 16 + l16;
        int ch = (ks * 4 + quad) ^ (row & 7);
        bf16x8 a = *(const bf16x8*)((const char*)sK + row * 128 + ch * 16);
        s[mt][0] = MFMA16(a, bq[0][ks], s[mt][0]);
        s[mt][1] = MFMA16(a, bq[1][ks], s[mt][1]);
      }
    }

#pragma unroll
    for (int qf = 0; qf < 2; qf++) {
      int row = qf * 16 + l16;
#pragma unroll
      for (int mt = 0; mt < 4; mt++) {
        float p0 = __expf(s[mt][qf][0]);
        float p1 = __expf(s[mt][qf][1]);
        float p2 = __expf(s[mt][qf][2]);
        float p3 = __expf(s[mt][qf][3]);
        lsum[qf] += (p0 + p1) + (p2 + p3);
        ushort4 st;
        st.x = f2bf(p0); st.y = f2bf(p1); st.z = f2bf(p2); st.w = f2bf(p3);
        int ch = (2 * mt + (quad >> 1)) ^ (row & 7);
        *(ushort4*)((char*)sPw + row * 128 + ch * 16 + (quad & 1) * 8) = st;
      }
    }
    asm volatile("s_waitcnt lgkmcnt(0)" ::: "memory");  // same-wave P write->read

    bf16x8 bp[2][2];
#pragma unroll
    for (int qf = 0; qf < 2; qf++) {
      int row = qf * 16 + l16;
#pragma unroll
      for (int c = 0; c < 2; c++) {
        int ch = (c * 4 + quad) ^ (row & 7);
        bp[qf][c] = *(const bf16x8*)((const char*)sPw + row * 128 + ch * 16);
      }
    }
#pragma unroll
    for (int c = 0; c < 2; c++) {
#pragma unroll
      for (int mt = 0; mt < 4; mt++) {
        int row = mt * 16 + l16;
        int ch = (c * 4 + quad) ^ (row & 7);
        bf16x8 a = *(const bf16x8*)((const char*)sV + row * 128 + ch * 16);
        oacc[mt][0] = MFMA16(a, bp[0][c], oacc[mt][0]);
        oacc[mt][1] = MFMA16(a, bp[1][c], oacc[mt][1]);
      }
    }
    __syncthreads();
  }

#pragma unroll
  for (int qf = 0; qf < 2; qf++) {
    lsum[qf] += __shfl_xor(lsum[qf], 16, 64);
    lsum[qf] += __shfl_xor(lsum[qf], 32, 64);
  }
  float inv0 = 1.f / lsum[0], inv1 = 1.f / lsum[1];

  int b = bh >> 4, h = bh & 15;
#pragma unroll
  for (int qf = 0; qf < 2; qf++) {
    int qg = q0 + wid * 32 + qf * 16 + l16;
    float inv = qf ? inv1 : inv0;
#pragma unroll
    for (int mt = 0; mt < 4; mt++) {
      int dk = mt * 16 + quad * 4;
      ushort4 st;
      st.x = f2bf(oacc[mt][qf][0] * inv);
      st.y = f2bf(oacc[mt][qf][1] * inv);
      st.z = f2bf(oacc[mt][qf][2] * inv);
      st.w = f2bf(oacc[mt][qf][3] * inv);
      *(ushort4*)(CTX + (((size_t)(b * 1024 + qg) * 16 + h) * 64 + dk)) = st;
    }
  }
}

// ---------------------------------------------------------------------------
extern "C" void kernel_launch(void* const* d_in, const int* in_sizes, int n_in,
                              void* d_out, int out_size, void* d_ws, size_t ws_size,
                              hipStream_t stream) {
  (void)in_sizes; (void)n_in; (void)out_size;
  const float* query = (const float*)d_in[0];
  const float* key_ = (const float*)d_in[1];
  const float* value = (const float*)d_in[2];
  const float* Wq = (const float*)d_in[3];
  const float* Wk = (const float*)d_in[4];
  const float* Wv = (const float*)d_in[5];
  const float* Wo = (const float*)d_in[6];
  const float* bo = (const float*)d_in[7];

  u16* ws = (u16*)d_ws;
  u16* WT = ws;                   // 4 x [1024][1024] bf16 (WTq,WTk,WTv,WoT)
  u16* X = ws + 4194304;          // 3 x [8192][1024] bf16 (Xq,Xk,Xv)
  u16* Qw = ws + 29360128;        // [B,H,L,DK]
  u16* Kw = ws + 37748736;        // [B,H,L,DK]
  u16* Vw = ws + 46137344;        // [B,H,DK,L] (fresh buffer; needs 104 MB ws)
  u16* Cw = X;                    // alias Xq (dead after projections)
  float* outp = (float*)d_out;

  prep<<<26624, 256, 0, stream>>>(Wq, Wk, Wv, Wo, query, key_, value, ws);
  // ws requirement: (46137344 + 8388608) u16 = 109051904 B
  gemm_qkv<<<dim3(8, 64, 3), 256, 0, stream>>>(WT, X, Qw, Kw, Vw);
  attn_k<<<dim3(8, 128), 256, 0, stream>>>(Qw, Kw, Vw, Cw);
  gemm_out<<<dim3(8, 64), 256, 0, stream>>>(WT + 3145728, Cw, outp, bo);
}